// Round 5
// baseline (31.650 us; speedup 1.0000x reference)
//
#include <hip/hip_runtime.h>

#define D_MODEL 256
#define SPECIAL_OFFSET 68      // 52 cards + 16 bet bins
#define NUM_SPECIAL 8
#define NUM_CONTEXT 16
#define LN_EPS 1e-5f

typedef float f32x4 __attribute__((ext_vector_type(4)));

// R1 structure (one 64-lane wave per token, one-shot), but block = 1024
// threads = 16 waves = 16 tokens per workgroup -> 8192 WGs instead of 32768.
// Per-wave work is identical to R1 (26.5 us); only the dispatch count drops.
// Lane owns 4 consecutive output channels (float4). token_id is wave-uniform
// -> uniform branches.
__global__ __launch_bounds__(1024) void ctx_emb_kernel(
    const int*   __restrict__ token_ids,        // [N]
    const float* __restrict__ context_features, // [N, 16]
    const float* __restrict__ special_table,    // [8, 256]
    const float* __restrict__ cls_w,            // [3, 256]
    const float* __restrict__ cls_b,            // [256]
    const float* __restrict__ cls_g,            // [256]
    const float* __restrict__ cls_be,           // [256]
    const float* __restrict__ ctx_w,            // [16, 256]
    const float* __restrict__ ctx_b,            // [256]
    const float* __restrict__ ctx_g,            // [256]
    const float* __restrict__ ctx_be,           // [256]
    float*       __restrict__ out,              // [N, 256]
    int n_tokens)
{
    const int wave = (int)((blockIdx.x * (unsigned)blockDim.x + threadIdx.x) >> 6);
    const int lane = threadIdx.x & 63;
    if (wave >= n_tokens) return;

    const int tid = token_ids[wave];   // wave-uniform -> broadcast
    const int d0  = lane * 4;

    f32x4 acc = {0.f, 0.f, 0.f, 0.f};

    // Special-token embedding (includes tokens 68 and 69!)
    if (tid >= SPECIAL_OFFSET && tid < SPECIAL_OFFSET + NUM_SPECIAL) {
        acc = *(const f32x4*)(special_table + (tid - SPECIAL_OFFSET) * D_MODEL + d0);
    }

    const bool is_cls = (tid == SPECIAL_OFFSET);       // CLS
    const bool is_ctx = (tid == SPECIAL_OFFSET + 1);   // CONTEXT

    if (is_cls || is_ctx) {
        const float* w  = is_cls ? cls_w  : ctx_w;
        const float* bb = is_cls ? cls_b  : ctx_b;
        const float* g  = is_cls ? cls_g  : ctx_g;
        const float* be = is_cls ? cls_be : ctx_be;
        const int    K  = is_cls ? 3 : NUM_CONTEXT;

        const float* f = context_features + (size_t)wave * NUM_CONTEXT;

        f32x4 h = *(const f32x4*)(bb + d0);
        for (int k = 0; k < K; ++k) {
            const float fk = f[k];
            const f32x4 wk = *(const f32x4*)(w + k * D_MODEL + d0);
            h.x = fmaf(fk, wk.x, h.x);
            h.y = fmaf(fk, wk.y, h.y);
            h.z = fmaf(fk, wk.z, h.z);
            h.w = fmaf(fk, wk.w, h.w);
        }

        // LayerNorm over 256 channels: wave-wide butterfly on (sum, sumsq)
        float s  = h.x + h.y + h.z + h.w;
        float sq = h.x * h.x + h.y * h.y + h.z * h.z + h.w * h.w;
        #pragma unroll
        for (int m = 1; m < 64; m <<= 1) {
            s  += __shfl_xor(s,  m, 64);
            sq += __shfl_xor(sq, m, 64);
        }
        const float mu  = s * (1.0f / D_MODEL);
        const float var = sq * (1.0f / D_MODEL) - mu * mu;
        const float rs  = rsqrtf(var + LN_EPS);

        const f32x4 gv = *(const f32x4*)(g  + d0);
        const f32x4 bv = *(const f32x4*)(be + d0);
        acc.x += fmaxf((h.x - mu) * rs * gv.x + bv.x, 0.f);
        acc.y += fmaxf((h.y - mu) * rs * gv.y + bv.y, 0.f);
        acc.z += fmaxf((h.z - mu) * rs * gv.z + bv.z, 0.f);
        acc.w += fmaxf((h.w - mu) * rs * gv.w + bv.w, 0.f);
    }

    *(f32x4*)(out + (size_t)wave * D_MODEL + d0) = acc;
}

extern "C" void kernel_launch(void* const* d_in, const int* in_sizes, int n_in,
                              void* d_out, int out_size, void* d_ws, size_t ws_size,
                              hipStream_t stream) {
    const int*   token_ids = (const int*)  d_in[0];
    const float* ctx_feat  = (const float*)d_in[1];
    const float* special   = (const float*)d_in[2];
    const float* cls_w     = (const float*)d_in[3];
    const float* cls_b     = (const float*)d_in[4];
    const float* cls_g     = (const float*)d_in[5];
    const float* cls_be    = (const float*)d_in[6];
    const float* ctx_w     = (const float*)d_in[7];
    const float* ctx_b     = (const float*)d_in[8];
    const float* ctx_g     = (const float*)d_in[9];
    const float* ctx_be    = (const float*)d_in[10];
    float*       out       = (float*)d_out;

    const int n_tokens = in_sizes[0];             // B*S = 131072
    const int waves_per_block = 1024 / 64;        // 16 tokens per block
    const int grid = (n_tokens + waves_per_block - 1) / waves_per_block;  // 8192

    ctx_emb_kernel<<<grid, 1024, 0, stream>>>(
        token_ids, ctx_feat, special,
        cls_w, cls_b, cls_g, cls_be,
        ctx_w, ctx_b, ctx_g, ctx_be,
        out, n_tokens);
}

// Round 6
// 25.983 us; speedup vs baseline: 1.2181x; 1.2181x over previous
//
#include <hip/hip_runtime.h>

#define D_MODEL 256
#define SPECIAL_OFFSET 68      // 52 cards + 16 bet bins
#define NUM_SPECIAL 8
#define NUM_CONTEXT 16
#define LN_EPS 1e-5f

typedef float f32x4 __attribute__((ext_vector_type(4)));

// One wave per token (R1 shape), but the row store is DECOUPLED from the
// token_id load: every wave stores zeros to its row immediately (issues with
// no dependency), then reads its wave-uniform tid via the SCALAR path
// (lgkmcnt, separate from the store's vmcnt). Only special waves (~10.5%)
// recompute the row and overwrite it after a vmcnt(0) guard (same-address
// store-store ordering within a wave needs the wait). 89.5% of output bytes
// become a pure dependency-free fill stream.
__global__ __launch_bounds__(256) void ctx_emb_kernel(
    const int*   __restrict__ token_ids,        // [N]
    const float* __restrict__ context_features, // [N, 16]
    const float* __restrict__ special_table,    // [8, 256]
    const float* __restrict__ cls_w,            // [3, 256]
    const float* __restrict__ cls_b,            // [256]
    const float* __restrict__ cls_g,            // [256]
    const float* __restrict__ cls_be,           // [256]
    const float* __restrict__ ctx_w,            // [16, 256]
    const float* __restrict__ ctx_b,            // [256]
    const float* __restrict__ ctx_g,            // [256]
    const float* __restrict__ ctx_be,           // [256]
    float*       __restrict__ out,              // [N, 256]
    int n_tokens)
{
    const int lane = threadIdx.x & 63;
    // Force wave index into an SGPR so token_ids[wave] selects s_load (SMEM).
    const int wib  = __builtin_amdgcn_readfirstlane((int)(threadIdx.x >> 6));
    const int wave = (int)blockIdx.x * 4 + wib;
    if (wave >= n_tokens) return;

    const int d0 = lane * 4;
    f32x4* orow = (f32x4*)(out + (size_t)wave * D_MODEL + d0);

    // (1) Dependency-free zero fill of the row — issues immediately.
    f32x4 z = {0.f, 0.f, 0.f, 0.f};
    *orow = z;

    // (2) Wave-uniform token id, scalar load path.
    const int tid = token_ids[wave];

    // Keep the zero-store and tid-load ABOVE the branch: forbid the compiler
    // from sinking the store into the branch arms (which would reintroduce
    // the load->store dependency for the common case).
    asm volatile("" ::: "memory");

    if (tid >= SPECIAL_OFFSET && tid < SPECIAL_OFFSET + NUM_SPECIAL) {
        f32x4 acc = *(const f32x4*)(special_table + (tid - SPECIAL_OFFSET) * D_MODEL + d0);

        const bool is_cls = (tid == SPECIAL_OFFSET);       // CLS
        const bool is_ctx = (tid == SPECIAL_OFFSET + 1);   // CONTEXT

        if (is_cls || is_ctx) {
            const float* w  = is_cls ? cls_w  : ctx_w;
            const float* bb = is_cls ? cls_b  : ctx_b;
            const float* g  = is_cls ? cls_g  : ctx_g;
            const float* be = is_cls ? cls_be : ctx_be;
            const int    K  = is_cls ? 3 : NUM_CONTEXT;

            const float* f = context_features + (size_t)wave * NUM_CONTEXT;

            f32x4 h = *(const f32x4*)(bb + d0);
            for (int k = 0; k < K; ++k) {
                const float fk = f[k];                     // uniform -> SGPR
                const f32x4 wk = *(const f32x4*)(w + k * D_MODEL + d0);
                h.x = fmaf(fk, wk.x, h.x);
                h.y = fmaf(fk, wk.y, h.y);
                h.z = fmaf(fk, wk.z, h.z);
                h.w = fmaf(fk, wk.w, h.w);
            }

            // LayerNorm over 256 channels: wave-wide butterfly on (sum, sumsq)
            float s  = h.x + h.y + h.z + h.w;
            float sq = h.x * h.x + h.y * h.y + h.z * h.z + h.w * h.w;
            #pragma unroll
            for (int m = 1; m < 64; m <<= 1) {
                s  += __shfl_xor(s,  m, 64);
                sq += __shfl_xor(sq, m, 64);
            }
            const float mu  = s * (1.0f / D_MODEL);
            const float var = sq * (1.0f / D_MODEL) - mu * mu;
            const float rs  = rsqrtf(var + LN_EPS);

            const f32x4 gv = *(const f32x4*)(g  + d0);
            const f32x4 bv = *(const f32x4*)(be + d0);
            acc.x += fmaxf((h.x - mu) * rs * gv.x + bv.x, 0.f);
            acc.y += fmaxf((h.y - mu) * rs * gv.y + bv.y, 0.f);
            acc.z += fmaxf((h.z - mu) * rs * gv.z + bv.z, 0.f);
            acc.w += fmaxf((h.w - mu) * rs * gv.w + bv.w, 0.f);
        }

        // Zero-store must be globally visible before the overwrite.
        asm volatile("s_waitcnt vmcnt(0)" ::: "memory");
        *orow = acc;
    }
}

extern "C" void kernel_launch(void* const* d_in, const int* in_sizes, int n_in,
                              void* d_out, int out_size, void* d_ws, size_t ws_size,
                              hipStream_t stream) {
    const int*   token_ids = (const int*)  d_in[0];
    const float* ctx_feat  = (const float*)d_in[1];
    const float* special   = (const float*)d_in[2];
    const float* cls_w     = (const float*)d_in[3];
    const float* cls_b     = (const float*)d_in[4];
    const float* cls_g     = (const float*)d_in[5];
    const float* cls_be    = (const float*)d_in[6];
    const float* ctx_w     = (const float*)d_in[7];
    const float* ctx_b     = (const float*)d_in[8];
    const float* ctx_g     = (const float*)d_in[9];
    const float* ctx_be    = (const float*)d_in[10];
    float*       out       = (float*)d_out;

    const int n_tokens = in_sizes[0];            // B*S = 131072
    const int waves_per_block = 256 / 64;        // 4 tokens per block
    const int grid = (n_tokens + waves_per_block - 1) / waves_per_block;

    ctx_emb_kernel<<<grid, 256, 0, stream>>>(
        token_ids, ctx_feat, special,
        cls_w, cls_b, cls_g, cls_be,
        ctx_w, ctx_b, ctx_g, ctx_be,
        out, n_tokens);
}